// Round 13
// baseline (256.845 us; speedup 1.0000x reference)
//
#include <hip/hip_runtime.h>

typedef __attribute__((ext_vector_type(8))) short  s16x8;
typedef __attribute__((ext_vector_type(8))) unsigned short u16x8;
typedef __attribute__((ext_vector_type(4))) float  f32x4;

constexpr float BN_EPS = 1e-5f;
#define DEV_INLINE __device__ __forceinline__

DEV_INLINE ushort f2bf(float f) {
  unsigned int u = __float_as_uint(f);
  return (ushort)((u + 0x7FFFu + ((u >> 16) & 1u)) >> 16);
}
DEV_INLINE float bf2f(ushort b) { return __uint_as_float(((unsigned int)b) << 16); }

DEV_INLINE unsigned int cvtpk(float a, float b) {
  unsigned int r;
  asm volatile("v_cvt_pk_bf16_f32 %0, %1, %2" : "=v"(r) : "v"(a), "v"(b));
  return r;
}

DEV_INLINE f32x4 mfma16(s16x8 a, s16x8 b, f32x4 c) {
  return __builtin_amdgcn_mfma_f32_16x16x32_bf16(a, b, c, 0, 0, 0);
}

// packed B-fragment index decode: r in [0,1024) -> (k, col16)
DEV_INLINE void decode_frag(int r, int& k, int& c16) {
  const int ks = r >> 9;
  const int l = (r >> 3) & 63;
  const int j = r & 7;
  k = ks * 32 + ((l >> 4) << 3) + j;
  c16 = l & 15;
}

// scalar BN finalize for one channel, all in registers
DEV_INLINE void bnFinReg(const float* __restrict__ sum, const float* __restrict__ sq,
                         const float* __restrict__ g, const float* __restrict__ b,
                         float invN, int ch, float& a, float& c) {
  float m = sum[ch] * invN;
  float v = fmaxf(sq[ch] * invN - m * m, 0.f);
  a = g[ch] * rsqrtf(v + BN_EPS);
  c = fmaf(-m, a, b[ch]);
}

// ---- pack W1|Ws (20 ct), Wk (9x4 ct), W3 (16 ct); zero stats region --------
__global__ void kPackW(const float* __restrict__ W1, const float* __restrict__ Ws,
                       const float* __restrict__ Wk, const float* __restrict__ W3,
                       ushort* __restrict__ WP1S, ushort* __restrict__ WPk,
                       ushort* __restrict__ WP3, float* __restrict__ statz) {
  int e = blockIdx.x * 256 + threadIdx.x;  // 73728 total
  if (e < 1280) statz[e] = 0.f;
  if (e < 20480) {
    int ct = e >> 10, r = e & 1023, k, c16;
    decode_frag(r, k, c16);
    float w = (ct < 4) ? W1[k * 64 + ct * 16 + c16] : Ws[k * 256 + (ct - 4) * 16 + c16];
    WP1S[e] = f2bf(w);
  } else if (e < 57344) {
    int e2 = e - 20480;
    int tap = e2 >> 12, r2 = e2 & 4095;
    int ct = r2 >> 10, k, c16;
    decode_frag(r2 & 1023, k, c16);
    WPk[e2] = f2bf(Wk[tap * 4096 + k * 64 + ct * 16 + c16]);
  } else {
    int e3 = e - 57344;
    int ct = e3 >> 10, k, c16;
    decode_frag(e3 & 1023, k, c16);
    WP3[e3] = f2bf(W3[k * 256 + ct * 16 + c16]);
  }
}

// load one A-fragment pair straight from f32 matrix (64 ch/row), converting
DEV_INLINE void loadFragF32(const float* __restrict__ X, int row, int ks,
                            s16x8& a0, s16x8& a1) {
  const float4* p0 = reinterpret_cast<const float4*>(X + (size_t)row * 64 + ks * 8);
  const float4* p1 = reinterpret_cast<const float4*>(X + (size_t)row * 64 + 32 + ks * 8);
  float4 x0 = p0[0], x1 = p0[1], y0 = p1[0], y1 = p1[1];
  union { s16x8 v; unsigned int d[4]; } u0, u1;
  u0.d[0] = cvtpk(x0.x, x0.y); u0.d[1] = cvtpk(x0.z, x0.w);
  u0.d[2] = cvtpk(x1.x, x1.y); u0.d[3] = cvtpk(x1.z, x1.w);
  u1.d[0] = cvtpk(y0.x, y0.y); u1.d[1] = cvtpk(y0.z, y0.w);
  u1.d[2] = cvtpk(y1.x, y1.y); u1.d[3] = cvtpk(y1.z, y1.w);
  a0 = u0.v;
  a1 = u1.v;
}

// ---- K1: colsum/colsq of X@[W1|Ws] (320 cols); writes Xb; LDS-free ---------
__global__ __launch_bounds__(256) void kStatsXW(const float* __restrict__ X,
                                                const ushort* __restrict__ WP,
                                                ushort* __restrict__ Xb,
                                                float* __restrict__ gsum,
                                                float* __restrict__ gsq,
                                                int N, int ntiles) {
  const int tid = threadIdx.x;
  const int l = tid & 63, w = tid >> 6;
  const int j = l & 15, ks = l >> 4;
  const u16x8* wp = (const u16x8*)WP;
  s16x8 wgt[5][2];
#pragma unroll
  for (int i = 0; i < 5; ++i)
#pragma unroll
    for (int jj = 0; jj < 2; ++jj) wgt[i][jj] = (s16x8)wp[((w * 5 + i) * 2 + jj) * 64 + l];
  float sA[5] = {0.f, 0.f, 0.f, 0.f, 0.f}, qA[5] = {0.f, 0.f, 0.f, 0.f, 0.f};
  const s16x8 zf = {0, 0, 0, 0, 0, 0, 0, 0};
  for (int t = blockIdx.x; t < ntiles; t += gridDim.x) {
#pragma unroll
    for (int rb = 0; rb < 4; ++rb) {
      const int row = t * 64 + rb * 16 + j;
      s16x8 a0 = zf, a1 = zf;
      if (row < N) {
        loadFragF32(X, row, ks, a0, a1);
        if (rb == w) {  // each wave persists its own row-block once
          char* xp = (char*)Xb + (size_t)row * 128 + ks * 16;
          *(s16x8*)xp = a0;
          *(s16x8*)(xp + 64) = a1;
        }
      }
#pragma unroll
      for (int i = 0; i < 5; ++i) {
        f32x4 acc = {0.f, 0.f, 0.f, 0.f};
        acc = mfma16(a0, wgt[i][0], acc);
        acc = mfma16(a1, wgt[i][1], acc);
        sA[i] += acc[0] + acc[1] + acc[2] + acc[3];
        qA[i] += acc[0] * acc[0] + acc[1] * acc[1] + acc[2] * acc[2] + acc[3] * acc[3];
      }
    }
  }
#pragma unroll
  for (int i = 0; i < 5; ++i) {
    float sp = sA[i], qp = qA[i];
    sp += __shfl_xor(sp, 16); sp += __shfl_xor(sp, 32);
    qp += __shfl_xor(qp, 16); qp += __shfl_xor(qp, 32);
    if (l < 16) {
      atomicAdd(&gsum[(w * 5 + i) * 16 + l], sp);
      atomicAdd(&gsq[(w * 5 + i) * 16 + l], qp);
    }
  }
}

// ---- K2: h1 = relu(a1*(Xb@W1)+c1) -> bf16; LDS-free ------------------------
__global__ __launch_bounds__(256) void kGemm1(const ushort* __restrict__ Xb,
                                              const ushort* __restrict__ WP,
                                              const float* __restrict__ sum1,
                                              const float* __restrict__ sq1,
                                              const float* __restrict__ g1,
                                              const float* __restrict__ b1,
                                              float invN, ushort* __restrict__ H1,
                                              int N, int ntiles) {
  const int tid = threadIdx.x;
  const int l = tid & 63, w = tid >> 6;
  const int j = l & 15, ks = l >> 4;
  const u16x8* wp = (const u16x8*)WP;
  const s16x8 wg0 = (s16x8)wp[(w * 2 + 0) * 64 + l];
  const s16x8 wg1 = (s16x8)wp[(w * 2 + 1) * 64 + l];
  const int col = w * 16 + j;
  float aj, cj;
  bnFinReg(sum1, sq1, g1, b1, invN, col, aj, cj);
  const s16x8 zf = {0, 0, 0, 0, 0, 0, 0, 0};
  for (int t = blockIdx.x; t < ntiles; t += gridDim.x) {
#pragma unroll
    for (int rb = 0; rb < 4; ++rb) {
      const int row = t * 64 + rb * 16 + j;
      s16x8 a0 = zf, a1 = zf;
      if (row < N) {
        const char* xp = (const char*)Xb + (size_t)row * 128 + ks * 16;
        a0 = *(const s16x8*)xp;
        a1 = *(const s16x8*)(xp + 64);
      }
      f32x4 acc = {0.f, 0.f, 0.f, 0.f};
      acc = mfma16(a0, wg0, acc);
      acc = mfma16(a1, wg1, acc);
#pragma unroll
      for (int reg = 0; reg < 4; ++reg) {
        const int gr = t * 64 + rb * 16 + ks * 4 + reg;
        if (gr < N)
          H1[(size_t)gr * 64 + col] =
              (ushort)cvtpk(fmaxf(fmaf(acc[reg], aj, cj), 0.f), 0.f);
      }
    }
  }
}

// ---- K3: Y2 = sum_k gather_k(h1) @ Wk[k] + BN2 stats (R10 proven) ----------
__global__ __launch_bounds__(256) void kConv(const ushort* __restrict__ H1,
                                             const int* __restrict__ nbr,
                                             const ushort* __restrict__ WPk,
                                             ushort* __restrict__ Y2b,
                                             float* __restrict__ gsum,
                                             float* __restrict__ gsq,
                                             int N, int ntiles, int tpb) {
  __shared__ float lsum[64], lsq[64];
  const int tid = threadIdx.x;
  if (tid < 64) { lsum[tid] = 0.f; lsq[tid] = 0.f; }
  __syncthreads();
  const int l = tid & 63, w = tid >> 6;
  const int lr = l & 15;
  const int ks = l >> 4;
  const u16x8* wp = (const u16x8*)WPk;
  float sAcc[4] = {0.f, 0.f, 0.f, 0.f}, qAcc[4] = {0.f, 0.f, 0.f, 0.f};
  const int t0 = blockIdx.x * tpb;
  const int t1 = (t0 + tpb < ntiles) ? (t0 + tpb) : ntiles;
  const s16x8 zf = {0, 0, 0, 0, 0, 0, 0, 0};
  for (int t = t0; t < t1; ++t) {
    const int row = t * 64 + w * 16 + lr;
    const bool valid = row < N;
    int srcs[9];
#pragma unroll
    for (int k = 0; k < 9; ++k)
      srcs[k] = valid ? nbr[(size_t)row * 9 + k] : -1;
    s16x8 A0[9], A1[9];
#pragma unroll
    for (int k = 0; k < 9; ++k) {
      const int sc = (srcs[k] < 0) ? 0 : srcs[k];
      const char* p = (const char*)H1 + (size_t)sc * 128 + ks * 16;
      A0[k] = *(const s16x8*)p;
      A1[k] = *(const s16x8*)(p + 64);
    }
#pragma unroll
    for (int k = 0; k < 9; ++k) {
      if (srcs[k] < 0) { A0[k] = zf; A1[k] = zf; }
    }
    f32x4 acc[4];
#pragma unroll
    for (int ct = 0; ct < 4; ++ct) acc[ct] = {0.f, 0.f, 0.f, 0.f};
    __builtin_amdgcn_s_setprio(1);
#pragma unroll
    for (int k = 0; k < 9; ++k) {
#pragma unroll
      for (int ct = 0; ct < 4; ++ct) {
        s16x8 b0 = (s16x8)wp[(size_t)((k * 4 + ct) * 2 + 0) * 64 + l];
        s16x8 b1 = (s16x8)wp[(size_t)((k * 4 + ct) * 2 + 1) * 64 + l];
        acc[ct] = mfma16(A0[k], b0, acc[ct]);
        acc[ct] = mfma16(A1[k], b1, acc[ct]);
      }
    }
    __builtin_amdgcn_s_setprio(0);
#pragma unroll
    for (int ct = 0; ct < 4; ++ct) {
      const f32x4 v = acc[ct];
      const int col = ct * 16 + lr;
#pragma unroll
      for (int reg = 0; reg < 4; ++reg) {
        const int gr = t * 64 + w * 16 + ks * 4 + reg;
        if (gr < N) Y2b[(size_t)gr * 64 + col] = (ushort)cvtpk(v[reg], v[reg]);
      }
      sAcc[ct] += v[0] + v[1] + v[2] + v[3];
      qAcc[ct] += v[0] * v[0] + v[1] * v[1] + v[2] * v[2] + v[3] * v[3];
    }
  }
#pragma unroll
  for (int ct = 0; ct < 4; ++ct) {
    float sp = sAcc[ct], qp = qAcc[ct];
    sp += __shfl_xor(sp, 16); sp += __shfl_xor(sp, 32);
    qp += __shfl_xor(qp, 16); qp += __shfl_xor(qp, 32);
    if (l < 16) {
      atomicAdd(&lsum[ct * 16 + l], sp);
      atomicAdd(&lsq[ct * 16 + l], qp);
    }
  }
  __syncthreads();
  if (tid < 64) {
    atomicAdd(&gsum[tid], lsum[tid]);
    atomicAdd(&gsq[tid], lsq[tid]);
  }
}

// load h2 A-fragment pair from Y2b with in-register BN2 affine + relu
DEV_INLINE void loadFragH2(const ushort* __restrict__ Y2b, int row, int ks,
                           const float* a2v, const float* c2v,  // 16 regs each
                           s16x8& h0, s16x8& h1) {
  const char* yp = (const char*)Y2b + (size_t)row * 128 + ks * 16;
  u16x8 y0 = *(const u16x8*)yp;
  u16x8 y1 = *(const u16x8*)(yp + 64);
  float f[8], g[8];
#pragma unroll
  for (int i = 0; i < 8; ++i) {
    f[i] = fmaxf(fmaf(bf2f(y0[i]), a2v[i], c2v[i]), 0.f);
    g[i] = fmaxf(fmaf(bf2f(y1[i]), a2v[8 + i], c2v[8 + i]), 0.f);
  }
  union { s16x8 v; unsigned int d[4]; } u0, u1;
#pragma unroll
  for (int i = 0; i < 4; ++i) {
    u0.d[i] = cvtpk(f[2 * i], f[2 * i + 1]);
    u1.d[i] = cvtpk(g[2 * i], g[2 * i + 1]);
  }
  h0 = u0.v;
  h1 = u1.v;
}

// ---- K4: BN3 stats of h2@W3 (h2 in-register); LDS-free ---------------------
__global__ __launch_bounds__(256) void kH2S3(const ushort* __restrict__ Y2b,
                                             const float* __restrict__ sum2,
                                             const float* __restrict__ sq2,
                                             const float* __restrict__ g2,
                                             const float* __restrict__ b2,
                                             float invN,
                                             const ushort* __restrict__ WP3,
                                             float* __restrict__ gsum,
                                             float* __restrict__ gsq,
                                             int N, int ntiles) {
  const int tid = threadIdx.x;
  const int l = tid & 63, w = tid >> 6;
  const int j = l & 15, ks = l >> 4;
  const u16x8* wp = (const u16x8*)WP3;
  s16x8 wgt[4][2];
#pragma unroll
  for (int i = 0; i < 4; ++i)
#pragma unroll
    for (int jj = 0; jj < 2; ++jj) wgt[i][jj] = (s16x8)wp[((w * 4 + i) * 2 + jj) * 64 + l];
  // per-lane input-channel BN2 params: chs [8ks,+8) and [32+8ks,+8)
  float a2v[16], c2v[16];
#pragma unroll
  for (int i = 0; i < 8; ++i) {
    bnFinReg(sum2, sq2, g2, b2, invN, ks * 8 + i, a2v[i], c2v[i]);
    bnFinReg(sum2, sq2, g2, b2, invN, 32 + ks * 8 + i, a2v[8 + i], c2v[8 + i]);
  }
  float sA[4] = {0.f, 0.f, 0.f, 0.f}, qA[4] = {0.f, 0.f, 0.f, 0.f};
  const s16x8 zf = {0, 0, 0, 0, 0, 0, 0, 0};
  for (int t = blockIdx.x; t < ntiles; t += gridDim.x) {
#pragma unroll
    for (int rb = 0; rb < 4; ++rb) {
      const int row = t * 64 + rb * 16 + j;
      s16x8 h0 = zf, h1 = zf;
      if (row < N) loadFragH2(Y2b, row, ks, a2v, c2v, h0, h1);
#pragma unroll
      for (int i = 0; i < 4; ++i) {
        f32x4 acc = {0.f, 0.f, 0.f, 0.f};
        acc = mfma16(h0, wgt[i][0], acc);
        acc = mfma16(h1, wgt[i][1], acc);
        sA[i] += acc[0] + acc[1] + acc[2] + acc[3];
        qA[i] += acc[0] * acc[0] + acc[1] * acc[1] + acc[2] * acc[2] + acc[3] * acc[3];
      }
    }
  }
#pragma unroll
  for (int i = 0; i < 4; ++i) {
    float sp = sA[i], qp = qA[i];
    sp += __shfl_xor(sp, 16); sp += __shfl_xor(sp, 32);
    qp += __shfl_xor(qp, 16); qp += __shfl_xor(qp, 32);
    if (l < 16) {
      atomicAdd(&gsum[(w * 4 + i) * 16 + l], sp);
      atomicAdd(&gsq[(w * 4 + i) * 16 + l], qp);
    }
  }
}

// ---- K5: out = relu(a3*(h2@W3) + aS*(Xb@Ws) + c3+cS); LDS-free -------------
__global__ __launch_bounds__(256) void kFinal(
    const ushort* __restrict__ Y2b, const ushort* __restrict__ Xb,
    const ushort* __restrict__ WP3, const ushort* __restrict__ WP1S,
    const float* __restrict__ sum2, const float* __restrict__ sq2,
    const float* __restrict__ g2, const float* __restrict__ b2,
    const float* __restrict__ sum3, const float* __restrict__ sq3,
    const float* __restrict__ g3, const float* __restrict__ b3,
    const float* __restrict__ sumS, const float* __restrict__ sqS,
    const float* __restrict__ gs, const float* __restrict__ bs,
    float invN, float* __restrict__ OUT, int N, int ntiles) {
  const int tid = threadIdx.x;
  const int l = tid & 63, w = tid >> 6;
  const int j = l & 15, ks = l >> 4;
  const u16x8* wp3 = (const u16x8*)WP3;
  const u16x8* wps = (const u16x8*)WP1S + 8 * 64;  // skip W1's 4 ct
  s16x8 w3[4][2], wsv[4][2];
#pragma unroll
  for (int i = 0; i < 4; ++i)
#pragma unroll
    for (int jj = 0; jj < 2; ++jj) {
      w3[i][jj]  = (s16x8)wp3[((w * 4 + i) * 2 + jj) * 64 + l];
      wsv[i][jj] = (s16x8)wps[((w * 4 + i) * 2 + jj) * 64 + l];
    }
  // input-channel BN2 params (16 chs this lane touches)
  float a2v[16], c2v[16];
#pragma unroll
  for (int i = 0; i < 8; ++i) {
    bnFinReg(sum2, sq2, g2, b2, invN, ks * 8 + i, a2v[i], c2v[i]);
    bnFinReg(sum2, sq2, g2, b2, invN, 32 + ks * 8 + i, a2v[8 + i], c2v[8 + i]);
  }
  // output-column BN3/BNs params (4 cols this lane owns)
  float a3r[4], aSr[4], ccr[4];
#pragma unroll
  for (int i = 0; i < 4; ++i) {
    const int col = (w * 4 + i) * 16 + j;
    float a3, c3, aS, cS;
    bnFinReg(sum3, sq3, g3, b3, invN, col, a3, c3);
    bnFinReg(sumS, sqS, gs, bs, invN, col, aS, cS);
    a3r[i] = a3;
    aSr[i] = aS;
    ccr[i] = c3 + cS;
  }
  const s16x8 zf = {0, 0, 0, 0, 0, 0, 0, 0};
  for (int t = blockIdx.x; t < ntiles; t += gridDim.x) {
#pragma unroll
    for (int rb = 0; rb < 4; ++rb) {
      const int row = t * 64 + rb * 16 + j;
      s16x8 ah0 = zf, ah1 = zf, ax0 = zf, ax1 = zf;
      if (row < N) {
        loadFragH2(Y2b, row, ks, a2v, c2v, ah0, ah1);
        const char* xp = (const char*)Xb + (size_t)row * 128 + ks * 16;
        ax0 = *(const s16x8*)xp;
        ax1 = *(const s16x8*)(xp + 64);
      }
#pragma unroll
      for (int i = 0; i < 4; ++i) {
        const int col = (w * 4 + i) * 16 + j;
        f32x4 acc3 = {0.f, 0.f, 0.f, 0.f};
        acc3 = mfma16(ah0, w3[i][0], acc3);
        acc3 = mfma16(ah1, w3[i][1], acc3);
        f32x4 accS = {0.f, 0.f, 0.f, 0.f};
        accS = mfma16(ax0, wsv[i][0], accS);
        accS = mfma16(ax1, wsv[i][1], accS);
#pragma unroll
        for (int reg = 0; reg < 4; ++reg) {
          const int gr = t * 64 + rb * 16 + ks * 4 + reg;
          if (gr < N) {
            const float ov =
                fmaxf(fmaf(acc3[reg], a3r[i], fmaf(accS[reg], aSr[i], ccr[i])), 0.f);
            __builtin_nontemporal_store(ov, &OUT[(size_t)gr * 256 + col]);
          }
        }
      }
    }
  }
}

extern "C" void kernel_launch(void* const* d_in, const int* in_sizes, int n_in,
                              void* d_out, int out_size, void* d_ws, size_t ws_size,
                              hipStream_t stream) {
  const float* X  = (const float*)d_in[0];
  const int*   nbr = (const int*)d_in[1];
  const float* W1 = (const float*)d_in[2];
  const float* g1 = (const float*)d_in[3];
  const float* b1 = (const float*)d_in[4];
  const float* Wk = (const float*)d_in[5];
  const float* g2 = (const float*)d_in[6];
  const float* b2 = (const float*)d_in[7];
  const float* W3 = (const float*)d_in[8];
  const float* g3 = (const float*)d_in[9];
  const float* b3 = (const float*)d_in[10];
  const float* Ws = (const float*)d_in[11];
  const float* gs = (const float*)d_in[12];
  const float* bs = (const float*)d_in[13];
  float* out = (float*)d_out;
  float* ws  = (float*)d_ws;

  const int N = in_sizes[0] / 64;
  const float invN = 1.f / (float)N;
  const int ntiles = (N + 63) / 64;

  // ws layout (float offsets)
  float* sum1S = ws + 0;     // [320]
  float* sq1S  = ws + 320;   // [320]
  float* sum2  = ws + 640;   // [64]
  float* sq2   = ws + 704;   // [64]
  float* sum3  = ws + 768;   // [256]
  float* sq3   = ws + 1024;  // [256]
  ushort* WP1S = (ushort*)(ws + 1280);   // 20480 bf16
  ushort* WPkP = (ushort*)(ws + 11520);  // 36864 bf16
  ushort* WP3P = (ushort*)(ws + 29952);  // 16384 bf16
  ushort* Xb   = (ushort*)(ws + 38144);                      // N*64 bf16
  ushort* Y2b  = (ushort*)(ws + 38144 + (size_t)N * 32);     // N*64 bf16
  ushort* H1b  = (ushort*)(ws + 38144 + (size_t)N * 64);     // N*64 bf16

  const int convGrid = 1024;
  const int tpb = (ntiles + convGrid - 1) / convGrid;

  kPackW<<<288, 256, 0, stream>>>(W1, Ws, Wk, W3, WP1S, WPkP, WP3P, ws);
  kStatsXW<<<508, 256, 0, stream>>>(X, WP1S, Xb, sum1S, sq1S, N, ntiles);
  kGemm1<<<508, 256, 0, stream>>>(Xb, WP1S, sum1S, sq1S, g1, b1, invN, H1b, N, ntiles);
  kConv<<<convGrid, 256, 0, stream>>>(H1b, nbr, WPkP, Y2b, sum2, sq2, N, ntiles, tpb);
  kH2S3<<<508, 256, 0, stream>>>(Y2b, sum2, sq2, g2, b2, invN, WP3P, sum3, sq3, N, ntiles);
  kFinal<<<512, 256, 0, stream>>>(Y2b, Xb, WP3P, WP1S, sum2, sq2, g2, b2,
                                  sum3, sq3, g3, b3, sum1S + 64, sq1S + 64,
                                  gs, bs, invN, out, N, ntiles);
}